// Round 5
// baseline (373.439 us; speedup 1.0000x reference)
//
#include <hip/hip_runtime.h>
#include <math.h>

#define EDGE_SCALE 0.17677669529663687f   // 32^-0.5
#define ATT_SCALE  0.15811388300841897f   // 40^-0.5
#define LN_EPS 1e-5f

typedef __attribute__((ext_vector_type(8))) short bf8;
typedef __attribute__((ext_vector_type(4))) float f32x4;

__device__ __forceinline__ f32x4 mfma16(bf8 a, bf8 b, f32x4 c) {
  return __builtin_amdgcn_mfma_f32_16x16x32_bf16(a, b, c, 0, 0, 0);
}
__device__ __forceinline__ unsigned short f2bf(float f) {
  union { float f; unsigned u; } v; v.f = f;
  unsigned r = v.u + 0x7FFF + ((v.u >> 16) & 1);
  return (unsigned short)(r >> 16);
}
__device__ __forceinline__ float bf2f(unsigned short h) {
  union { unsigned u; float f; } v; v.u = ((unsigned)h) << 16;
  return v.f;
}
__device__ __forceinline__ float wave_sum(float v) {
  #pragma unroll
  for (int o = 32; o > 0; o >>= 1) v += __shfl_xor(v, o);
  return v;
}

// node[b,n,c] = x[b,c,n]; also bf16 copy
__global__ __launch_bounds__(256) void k_trans(const float* __restrict__ x,
    float* __restrict__ node, unsigned short* __restrict__ nodebf) {
  __shared__ float tile[32][33];
  const int b = blockIdx.z;
  const int n0 = blockIdx.x * 32, c0 = blockIdx.y * 32;
  const int tx = threadIdx.x & 31, ty = threadIdx.x >> 5;
  #pragma unroll
  for (int k = 0; k < 4; ++k) {
    int c = c0 + ty + 8 * k;
    tile[ty + 8 * k][tx] = x[((size_t)b * 320 + c) * 1024 + n0 + tx];
  }
  __syncthreads();
  #pragma unroll
  for (int k = 0; k < 4; ++k) {
    int n = n0 + ty + 8 * k;
    float v = tile[tx][ty + 8 * k];
    size_t idx = ((size_t)b * 1024 + n) * 320 + c0 + tx;
    node[idx] = v;
    nodebf[idx] = f2bf(v);
  }
}

__global__ __launch_bounds__(320) void k_svec(const float* __restrict__ da,
    const float* __restrict__ fw, const float* __restrict__ fb, float* __restrict__ sv) {
  __shared__ float ds[64];
  const int b = blockIdx.x, t = threadIdx.x;
  if (t < 64) {
    float a = 0.f;
    #pragma unroll
    for (int i = 0; i < 16; ++i) a += da[b * 1024 + i * 64 + t];
    ds[t] = a;
  }
  __syncthreads();
  if (t < 320) {
    float acc = 16.f * fb[t];
    #pragma unroll
    for (int e = 0; e < 64; ++e) acc = fmaf(ds[e], fw[t * 64 + e], acc);
    sv[b * 320 + t] = acc;
  }
}

// convert weights fp32->bf16 (qk_w | qkv_w | proj_w concatenated)
__global__ void k_wcvt(const float* __restrict__ a, int na,
                       const float* __restrict__ b, int nb,
                       const float* __restrict__ c, int nc,
                       unsigned short* __restrict__ out) {
  int tot = na + nb + nc;
  for (int i = blockIdx.x * blockDim.x + threadIdx.x; i < tot; i += gridDim.x * blockDim.x) {
    float v = (i < na) ? a[i] : ((i < na + nb) ? b[i - na] : c[i - na - nb]);
    out[i] = f2bf(v);
  }
}

// MFMA GEMM: C[2048, Ncols] = A[2048,320]bf16 @ W[Ncols,320]bf16^T (+bias)
// mode 0: p0 fp32 [row*320+col]
// mode 1: col<320 -> qe bf16 [B,N,320]; else ke bf16 [B,N,320]
// mode 2: q->p0 [B,H,N,64]bf16 (d>=40 zero-padded); k->p1 same; v->p2 [B,H,48,1024]bf16
// mode 3: p0 fp32 [(b*320+col)*1024+n] via LDS transpose
__global__ __launch_bounds__(256, 4) void k_mgemm(
    const unsigned short* __restrict__ A, const unsigned short* __restrict__ W,
    const float* __restrict__ bias, void* p0, void* p1, void* p2, int mode) {
  __shared__ float smem[64 * 65];
  const int t = threadIdx.x, w = t >> 6, lane = t & 63;
  const int q16 = lane >> 4, l16 = lane & 15;
  const int rt = blockIdx.x * 64, jt = blockIdx.y * 64;
  f32x4 acc[4];
  #pragma unroll
  for (int i = 0; i < 4; ++i)
    #pragma unroll
    for (int j = 0; j < 4; ++j) acc[i][j] = 0.f;
  const unsigned short* ap = A + (size_t)(rt + 16 * w + l16) * 320 + q16 * 8;
  const unsigned short* wp = W + (size_t)(jt + l16) * 320 + q16 * 8;
  for (int kc = 0; kc < 10; ++kc) {
    bf8 af = *(const bf8*)(ap + kc * 32);
    #pragma unroll
    for (int ct = 0; ct < 4; ++ct) {
      bf8 bf = *(const bf8*)(wp + (size_t)ct * 16 * 320 + kc * 32);
      acc[ct] = mfma16(af, bf, acc[ct]);
    }
  }
  if (mode == 0 || mode == 1) {
    #pragma unroll
    for (int ct = 0; ct < 4; ++ct) {
      int col = jt + ct * 16 + l16;
      float bv = bias ? bias[col] : 0.f;
      #pragma unroll
      for (int r = 0; r < 4; ++r) {
        int row = rt + 16 * w + q16 * 4 + r;
        float v = acc[ct][r] + bv;
        if (mode == 0) {
          ((float*)p0)[(size_t)row * 320 + col] = v;
        } else {
          if (col < 320) ((unsigned short*)p0)[(size_t)row * 320 + col] = f2bf(v);
          else           ((unsigned short*)p1)[(size_t)row * 320 + col - 320] = f2bf(v);
        }
      }
    }
  } else if (mode == 2) {
    const int part = jt / 320;
    if (part < 2) {
      unsigned short* dst = (unsigned short*)(part == 0 ? p0 : p1);
      #pragma unroll
      for (int ct = 0; ct < 4; ++ct) {
        int col = jt + ct * 16 + l16;
        float bv = bias[col];
        int rem = col - part * 320;
        int h = rem / 40, d = rem % 40;
        #pragma unroll
        for (int r = 0; r < 4; ++r) {
          int row = rt + 16 * w + q16 * 4 + r;
          int b = row >> 10, n = row & 1023;
          size_t base = (((size_t)b * 8 + h) * 1024 + n) * 64;
          dst[base + d] = f2bf(acc[ct][r] + bv);
          if (d < 24) dst[base + 40 + d] = 0;
        }
      }
    } else {
      unsigned short* vt_t = (unsigned short*)smem;       // [64][72]
      #pragma unroll
      for (int ct = 0; ct < 4; ++ct) {
        int col = jt + ct * 16 + l16;
        float bv = bias[col];
        #pragma unroll
        for (int r = 0; r < 4; ++r)
          vt_t[(ct * 16 + l16) * 72 + 16 * w + q16 * 4 + r] = f2bf(acc[ct][r] + bv);
      }
      __syncthreads();
      const int cl = t >> 2, seg = t & 3;
      int rem = (jt - 640) + cl;
      int h = rem / 40, d = rem % 40;
      int b = rt >> 10, n = (rt & 1023) + seg * 16;
      const float4* lp = (const float4*)&vt_t[cl * 72 + seg * 16];
      float4 a0 = lp[0], a1 = lp[1];
      float4* gp = (float4*)((unsigned short*)p2 +
                             (((size_t)b * 8 + h) * 48 + d) * 1024 + n);
      gp[0] = a0; gp[1] = a1;
    }
  } else {
    #pragma unroll
    for (int ct = 0; ct < 4; ++ct) {
      int col = jt + ct * 16 + l16;
      float bv = bias[col];
      #pragma unroll
      for (int r = 0; r < 4; ++r)
        smem[(16 * w + q16 * 4 + r) * 65 + ct * 16 + l16] = acc[ct][r] + bv;
    }
    __syncthreads();
    const int cl = t >> 2, seg = t & 3;
    int b = rt >> 10, n = (rt & 1023) + seg * 16;
    float* orow = (float*)p0 + ((size_t)b * 320 + jt + cl) * 1024 + n;
    #pragma unroll
    for (int i2 = 0; i2 < 4; ++i2) {
      float4 vv;
      vv.x = smem[(seg * 16 + i2 * 4 + 0) * 65 + cl];
      vv.y = smem[(seg * 16 + i2 * 4 + 1) * 65 + cl];
      vv.z = smem[(seg * 16 + i2 * 4 + 2) * 65 + cl];
      vv.w = smem[(seg * 16 + i2 * 4 + 3) * 65 + cl];
      ((float4*)orow)[i2] = vv;
    }
  }
}

// Fused edge init: edge = softmax(qe @ ke^T * EDGE_SCALE) per row.
// Block = (16-row tile, b), 512 thr, 8 waves; wave w owns m-cols [128w,128w+128).
// No max-subtraction (logits ~ +-0.05, fp32-safe).
__global__ __launch_bounds__(512, 2) void k_edge3(
    const unsigned short* __restrict__ qe, const unsigned short* __restrict__ ke,
    float* __restrict__ edge) {
  __shared__ float zred[8][16];
  const int t = threadIdx.x, w = t >> 6, lane = t & 63;
  const int q16 = lane >> 4, l16 = lane & 15;
  const int n0 = blockIdx.x * 16, b = blockIdx.y;
  const unsigned short* qp = qe + ((size_t)(b * 1024 + n0 + l16)) * 320 + q16 * 8;
  bf8 af[10];
  #pragma unroll
  for (int kc = 0; kc < 10; ++kc) af[kc] = *(const bf8*)(qp + kc * 32);
  f32x4 acc[8];
  #pragma unroll
  for (int i = 0; i < 8; ++i)
    #pragma unroll
    for (int j = 0; j < 4; ++j) acc[i][j] = 0.f;
  const unsigned short* kp = ke + ((size_t)(b * 1024 + w * 128 + l16)) * 320 + q16 * 8;
  #pragma unroll
  for (int mt = 0; mt < 8; ++mt) {
    const unsigned short* kpt = kp + (size_t)mt * 16 * 320;
    #pragma unroll
    for (int kc = 0; kc < 10; ++kc) {
      bf8 bf = *(const bf8*)(kpt + kc * 32);
      acc[mt] = mfma16(af[kc], bf, acc[mt]);
    }
  }
  float zp[4] = {0.f, 0.f, 0.f, 0.f};
  #pragma unroll
  for (int mt = 0; mt < 8; ++mt)
    #pragma unroll
    for (int r = 0; r < 4; ++r) {
      float e = __expf(acc[mt][r] * EDGE_SCALE);
      acc[mt][r] = e;
      zp[r] += e;
    }
  #pragma unroll
  for (int r = 0; r < 4; ++r)
    #pragma unroll
    for (int o = 1; o <= 8; o <<= 1) zp[r] += __shfl_xor(zp[r], o);
  if (l16 == 0) {
    #pragma unroll
    for (int r = 0; r < 4; ++r) zred[w][q16 * 4 + r] = zp[r];
  }
  __syncthreads();
  float inv[4];
  #pragma unroll
  for (int r = 0; r < 4; ++r) {
    float s = 0.f;
    #pragma unroll
    for (int ww = 0; ww < 8; ++ww) s += zred[ww][q16 * 4 + r];
    inv[r] = 1.f / s;
  }
  #pragma unroll
  for (int r = 0; r < 4; ++r) {
    float* ep = edge + ((size_t)(b * 1024 + n0 + q16 * 4 + r)) * 1024 + w * 128 + l16;
    #pragma unroll
    for (int mt = 0; mt < 8; ++mt) ep[mt * 16] = acc[mt][r] * inv[r];
  }
}

// y_bf16 = LN(diag*LN(node)*s + LN(node)) per row; wave = 1 row.
__global__ __launch_bounds__(256) void k_ln(const float* __restrict__ node,
    const float* __restrict__ edge, const float* __restrict__ sv,
    const float* __restrict__ g1, const float* __restrict__ b1,
    const float* __restrict__ g2, const float* __restrict__ b2,
    unsigned short* __restrict__ y) {
  const int w = threadIdx.x >> 6, lane = threadIdx.x & 63;
  const int row = blockIdx.x * 4 + w;
  const int b = row >> 10, n = row & 1023;
  const float* xr = node + (size_t)row * 320;
  float x[5];
  #pragma unroll
  for (int i = 0; i < 5; ++i) x[i] = xr[lane + 64 * i];
  float s = x[0] + x[1] + x[2] + x[3] + x[4];
  float mean = wave_sum(s) * (1.f / 320.f);
  float v = 0.f;
  #pragma unroll
  for (int i = 0; i < 5; ++i) { float d = x[i] - mean; v += d * d; }
  float rstd = rsqrtf(wave_sum(v) * (1.f / 320.f) + LN_EPS);
  float diag = edge[(size_t)row * 1024 + n];
  float n2[5];
  #pragma unroll
  for (int i = 0; i < 5; ++i) {
    int c = lane + 64 * i;
    float nt = (x[i] - mean) * rstd * g1[c] + b1[c];
    n2[i] = diag * nt * sv[b * 320 + c] + nt;
  }
  s = n2[0] + n2[1] + n2[2] + n2[3] + n2[4];
  float mean2 = wave_sum(s) * (1.f / 320.f);
  v = 0.f;
  #pragma unroll
  for (int i = 0; i < 5; ++i) { float d = n2[i] - mean2; v += d * d; }
  float rstd2 = rsqrtf(wave_sum(v) * (1.f / 320.f) + LN_EPS);
  unsigned short* yr = y + (size_t)row * 320;
  #pragma unroll
  for (int i = 0; i < 5; ++i) {
    int c = lane + 64 * i;
    yr[c] = f2bf((n2[i] - mean2) * rstd2 * g2[c] + b2[c]);
  }
}

// Fully fused attention layer: block = (b, 16-row tile), 512 thr, 8 waves.
// Wave w owns m-cols [128w, 128w+128). Loops all 8 heads:
//   scores (MFMA) -> exp (no max) -> cross-wave Z -> t accum (regs) ->
//   AV (MFMA on unnormalized e, invZ-scaled, LDS atomic accumulate).
// End: wsum softmax (with max), edge += t, attbf = AV + wsum. No thbuf.
__global__ __launch_bounds__(512, 2) void k_attn2(
    const unsigned short* __restrict__ qbf, const unsigned short* __restrict__ kbf,
    const unsigned short* __restrict__ vtb, float* __restrict__ edge,
    unsigned short* __restrict__ attbf,
    const float* __restrict__ ew, const float* __restrict__ eb,
    const float* __restrict__ rw, const float* __restrict__ rb) {
  __shared__ float edge_lds[16][1028];            // 65.8 KB
  __shared__ unsigned short a_lds[8][16][136];    // 34.8 KB per-wave e-staging
  __shared__ float att_lds[16][330];              // 21.1 KB AV accumulator
  __shared__ float zred[2][8][16];
  __shared__ float wredm[8][16], wreds[8][16], wredn[8][16];
  __shared__ float wsum_sh[16];
  const int t = threadIdx.x, w = t >> 6, lane = t & 63;
  const int q16 = lane >> 4, l16 = lane & 15;
  const int n0 = blockIdx.x * 16, b = blockIdx.y;
  const size_t bh0 = (size_t)b * 8;
  // preload edge rows + zero att accumulator
  {
    const float4* src = (const float4*)(edge + ((size_t)(b * 1024 + n0)) * 1024);
    for (int i = t; i < 4096; i += 512) {
      int row = i >> 8, c4 = i & 255;
      ((float4*)&edge_lds[row][0])[c4] = src[(row << 8) + c4];
    }
    for (int i = t; i < 16 * 330; i += 512) (&att_lds[0][0])[i] = 0.f;
  }
  __syncthreads();
  const float rbv = rb[0];
  float t_reg[8][4];
  #pragma unroll
  for (int mt = 0; mt < 8; ++mt)
    #pragma unroll
    for (int r = 0; r < 4; ++r) t_reg[mt][r] = rbv;
  #pragma unroll 1
  for (int h = 0; h < 8; ++h) {
    const size_t bh = bh0 + h;
    const float ewh = ew[h], ebh = eb[h], rwh = rw[h];
    // Q frags (16 rows x K=64)
    const unsigned short* qp = qbf + (bh * 1024 + n0 + l16) * 64 + q16 * 8;
    bf8 af0 = *(const bf8*)(qp);
    bf8 af1 = *(const bf8*)(qp + 32);
    // scores on wave's m-range
    f32x4 acc[8];
    #pragma unroll
    for (int i = 0; i < 8; ++i)
      #pragma unroll
      for (int j = 0; j < 4; ++j) acc[i][j] = 0.f;
    const unsigned short* kp = kbf + (bh * 1024 + w * 128 + l16) * 64 + q16 * 8;
    #pragma unroll
    for (int mt = 0; mt < 8; ++mt) {
      const unsigned short* kpt = kp + (size_t)mt * 16 * 64;
      bf8 b0 = *(const bf8*)(kpt);
      bf8 b1 = *(const bf8*)(kpt + 32);
      acc[mt] = mfma16(af0, b0, acc[mt]);
      acc[mt] = mfma16(af1, b1, acc[mt]);
    }
    // bias + exp + Z partial; stash unnormalized e (bf16) in per-wave LDS
    float zp[4] = {0.f, 0.f, 0.f, 0.f};
    #pragma unroll
    for (int mt = 0; mt < 8; ++mt)
      #pragma unroll
      for (int r = 0; r < 4; ++r) {
        float ev = edge_lds[q16 * 4 + r][w * 128 + mt * 16 + l16];
        float s = fmaf(acc[mt][r], ATT_SCALE, fmaf(ev, ewh, ebh));
        acc[mt][r] = s;
        float e = __expf(s);
        zp[r] += e;
        a_lds[w][q16 * 4 + r][mt * 16 + l16] = f2bf(e);
      }
    #pragma unroll
    for (int r = 0; r < 4; ++r)
      #pragma unroll
      for (int o = 1; o <= 8; o <<= 1) zp[r] += __shfl_xor(zp[r], o);
    if (l16 == 0) {
      #pragma unroll
      for (int r = 0; r < 4; ++r) zred[h & 1][w][q16 * 4 + r] = zp[r];
    }
    __syncthreads();
    float invZ[4];
    #pragma unroll
    for (int r = 0; r < 4; ++r) {
      float s = 0.f;
      #pragma unroll
      for (int ww = 0; ww < 8; ++ww) s += zred[h & 1][ww][q16 * 4 + r];
      invZ[r] = 1.f / s;
    }
    // t accumulation: t += rw*(a + s)
    #pragma unroll
    for (int mt = 0; mt < 8; ++mt)
      #pragma unroll
      for (int r = 0; r < 4; ++r) {
        float e = __expf(acc[mt][r]);
        t_reg[mt][r] = fmaf(rwh, fmaf(e, invZ[r], acc[mt][r]), t_reg[mt][r]);
      }
    // AV partial on wave's m-range (A = unnormalized e from own a_lds)
    f32x4 oacc[3];
    #pragma unroll
    for (int i = 0; i < 3; ++i)
      #pragma unroll
      for (int j = 0; j < 4; ++j) oacc[i][j] = 0.f;
    #pragma unroll
    for (int kk = 0; kk < 4; ++kk) {
      bf8 afv = *(const bf8*)(&a_lds[w][l16][kk * 32 + q16 * 8]);
      const unsigned short* vp = vtb + (bh * 48 + l16) * 1024 + w * 128 + kk * 32 + q16 * 8;
      #pragma unroll
      for (int nt = 0; nt < 3; ++nt) {
        bf8 bfv = *(const bf8*)(vp + (size_t)nt * 16 * 1024);
        oacc[nt] = mfma16(afv, bfv, oacc[nt]);
      }
    }
    #pragma unroll
    for (int nt = 0; nt < 3; ++nt)
      #pragma unroll
      for (int r = 0; r < 4; ++r) {
        int d = nt * 16 + l16;
        if (d < 40)
          atomicAdd(&att_lds[q16 * 4 + r][h * 40 + d], oacc[nt][r] * invZ[r]);
      }
  }
  // ---- wsum = sum(softmax(t)*t) per row (max-subtracted) ----
  float pmx[4] = {-3.4e38f, -3.4e38f, -3.4e38f, -3.4e38f};
  #pragma unroll
  for (int mt = 0; mt < 8; ++mt)
    #pragma unroll
    for (int r = 0; r < 4; ++r) pmx[r] = fmaxf(pmx[r], t_reg[mt][r]);
  #pragma unroll
  for (int r = 0; r < 4; ++r)
    #pragma unroll
    for (int o = 1; o <= 8; o <<= 1) pmx[r] = fmaxf(pmx[r], __shfl_xor(pmx[r], o));
  if (l16 == 0) {
    #pragma unroll
    for (int r = 0; r < 4; ++r) wredm[w][q16 * 4 + r] = pmx[r];
  }
  __syncthreads();
  float mrow[4], sp[4] = {0.f, 0.f, 0.f, 0.f}, np[4] = {0.f, 0.f, 0.f, 0.f};
  #pragma unroll
  for (int r = 0; r < 4; ++r) {
    float m = -3.4e38f;
    #pragma unroll
    for (int ww = 0; ww < 8; ++ww) m = fmaxf(m, wredm[ww][q16 * 4 + r]);
    mrow[r] = m;
  }
  #pragma unroll
  for (int mt = 0; mt < 8; ++mt)
    #pragma unroll
    for (int r = 0; r < 4; ++r) {
      float e = __expf(t_reg[mt][r] - mrow[r]);
      sp[r] += e;
      np[r] = fmaf(e, t_reg[mt][r], np[r]);
    }
  #pragma unroll
  for (int r = 0; r < 4; ++r)
    #pragma unroll
    for (int o = 1; o <= 8; o <<= 1) {
      sp[r] += __shfl_xor(sp[r], o);
      np[r] += __shfl_xor(np[r], o);
    }
  if (l16 == 0) {
    #pragma unroll
    for (int r = 0; r < 4; ++r) { wreds[w][q16 * 4 + r] = sp[r]; wredn[w][q16 * 4 + r] = np[r]; }
  }
  // edge += t (global, from edge_lds + regs)
  #pragma unroll
  for (int r = 0; r < 4; ++r) {
    float* ep = edge + ((size_t)(b * 1024 + n0 + q16 * 4 + r)) * 1024 + w * 128 + l16;
    #pragma unroll
    for (int mt = 0; mt < 8; ++mt)
      ep[mt * 16] = edge_lds[q16 * 4 + r][w * 128 + mt * 16 + l16] + t_reg[mt][r];
  }
  __syncthreads();
  if (w == 0 && l16 == 0) {
    #pragma unroll
    for (int r = 0; r < 4; ++r) {
      float S = 0.f, N = 0.f;
      #pragma unroll
      for (int ww = 0; ww < 8; ++ww) { S += wreds[ww][q16 * 4 + r]; N += wredn[ww][q16 * 4 + r]; }
      wsum_sh[q16 * 4 + r] = N / S;
    }
  }
  __syncthreads();
  // attbf = AV + wsum (bf16, row-contiguous)
  for (int i = t; i < 5120; i += 512) {
    int row = i / 320, c = i - row * 320;
    attbf[((size_t)(b * 1024 + n0 + row)) * 320 + c] = f2bf(att_lds[row][c] + wsum_sh[row]);
  }
}

extern "C" void kernel_launch(void* const* d_in, const int* in_sizes, int n_in,
                              void* d_out, int out_size, void* d_ws, size_t ws_size,
                              hipStream_t stream) {
  const float* x      = (const float*)d_in[0];
  const float* da     = (const float*)d_in[1];
  const float* qk_w   = (const float*)d_in[2];
  const float* fcp_w  = (const float*)d_in[3];
  const float* fcp_b  = (const float*)d_in[4];
  const float* ln1_g  = (const float*)d_in[5];
  const float* ln1_b  = (const float*)d_in[6];
  const float* gln_g  = (const float*)d_in[7];
  const float* gln_b  = (const float*)d_in[8];
  const float* qkv_w  = (const float*)d_in[9];
  const float* qkv_b  = (const float*)d_in[10];
  const float* proj_w = (const float*)d_in[11];
  const float* proj_b = (const float*)d_in[12];
  const float* exp_w  = (const float*)d_in[13];
  const float* exp_b  = (const float*)d_in[14];
  const float* red_w  = (const float*)d_in[15];
  const float* red_b  = (const float*)d_in[16];
  float* ws = (float*)d_ws;
  float* node  = ws + 0;                                   // 655360
  unsigned short* ybf   = (unsigned short*)(ws + 655360);  // 327680 fl
  unsigned short* attbf = (unsigned short*)(ws + 1638400); // 327680 fl
  float* edge  = ws + 1966080;                             // 2097152
  float* svec  = ws + 4063232;                             // 640
  unsigned short* nodebf = (unsigned short*)(ws + 4063872);// 327680 fl
  unsigned short* qe   = (unsigned short*)(ws + 4391552);  // 327680 fl
  unsigned short* ke   = (unsigned short*)(ws + 4719232);  // 327680 fl
  unsigned short* qbf  = (unsigned short*)(ws + 5046912);  // 524288 fl
  unsigned short* kbf  = (unsigned short*)(ws + 5571200);  // 524288 fl
  unsigned short* vtb  = (unsigned short*)(ws + 6095488);  // 393216 fl
  unsigned short* wbf  = (unsigned short*)(ws + 6488704);  // 512000 fl
  float* out = (float*)d_out;
  unsigned short* qk_wb   = wbf;
  unsigned short* qkv_wb  = wbf + 204800;
  unsigned short* proj_wb = wbf + 819200;

  hipLaunchKernelGGL(k_trans, dim3(32, 10, 2), dim3(256), 0, stream, x, node, nodebf);
  hipLaunchKernelGGL(k_svec, dim3(2), dim3(320), 0, stream, da, fcp_w, fcp_b, svec);
  hipLaunchKernelGGL(k_wcvt, dim3(512), dim3(256), 0, stream,
                     qk_w, 204800, qkv_w, 614400, proj_w, 204800, wbf);
  hipLaunchKernelGGL(k_mgemm, dim3(32, 10), dim3(256), 0, stream,
                     nodebf, qk_wb, (const float*)nullptr, qe, ke, (void*)nullptr, 1);
  hipLaunchKernelGGL(k_edge3, dim3(64, 2), dim3(512), 0, stream, qe, ke, edge);
  for (int l = 0; l < 2; ++l) {
    hipLaunchKernelGGL(k_ln, dim3(512), dim3(256), 0, stream, node, edge, svec,
                       ln1_g + l * 320, ln1_b + l * 320, gln_g + l * 320, gln_b + l * 320, ybf);
    hipLaunchKernelGGL(k_mgemm, dim3(32, 15), dim3(256), 0, stream,
                       ybf, qkv_wb + (size_t)l * 307200, qkv_b + l * 960, qbf, kbf, vtb, 2);
    hipLaunchKernelGGL(k_attn2, dim3(64, 2), dim3(512), 0, stream,
                       qbf, kbf, vtb, edge, attbf,
                       exp_w + l * 8, exp_b + l * 8, red_w + l * 8, red_b + l);
    if (l == 0)
      hipLaunchKernelGGL(k_mgemm, dim3(32, 5), dim3(256), 0, stream,
                         attbf, proj_wb, proj_b, node, (void*)nullptr, (void*)nullptr, 0);
    else
      hipLaunchKernelGGL(k_mgemm, dim3(32, 5), dim3(256), 0, stream,
                         attbf, proj_wb + 102400, proj_b + 320, out,
                         (void*)nullptr, (void*)nullptr, 3);
  }
}

// Round 6
// 340.777 us; speedup vs baseline: 1.0958x; 1.0958x over previous
//
#include <hip/hip_runtime.h>
#include <math.h>

#define EDGE_SCALE 0.17677669529663687f   // 32^-0.5
#define ATT_SCALE  0.15811388300841897f   // 40^-0.5
#define LN_EPS 1e-5f

typedef __attribute__((ext_vector_type(8))) short bf8;
typedef __attribute__((ext_vector_type(4))) float f32x4;

__device__ __forceinline__ f32x4 mfma16(bf8 a, bf8 b, f32x4 c) {
  return __builtin_amdgcn_mfma_f32_16x16x32_bf16(a, b, c, 0, 0, 0);
}
__device__ __forceinline__ unsigned short f2bf(float f) {
  union { float f; unsigned u; } v; v.f = f;
  unsigned r = v.u + 0x7FFF + ((v.u >> 16) & 1);
  return (unsigned short)(r >> 16);
}
__device__ __forceinline__ float bf2f(unsigned short h) {
  union { unsigned u; float f; } v; v.u = ((unsigned)h) << 16;
  return v.f;
}
__device__ __forceinline__ float wave_max(float v) {
  #pragma unroll
  for (int o = 32; o > 0; o >>= 1) v = fmaxf(v, __shfl_xor(v, o));
  return v;
}
__device__ __forceinline__ float wave_sum(float v) {
  #pragma unroll
  for (int o = 32; o > 0; o >>= 1) v += __shfl_xor(v, o);
  return v;
}

// node[b,n,c] = x[b,c,n]; also bf16 copy
__global__ __launch_bounds__(256) void k_trans(const float* __restrict__ x,
    float* __restrict__ node, unsigned short* __restrict__ nodebf) {
  __shared__ float tile[32][33];
  const int b = blockIdx.z;
  const int n0 = blockIdx.x * 32, c0 = blockIdx.y * 32;
  const int tx = threadIdx.x & 31, ty = threadIdx.x >> 5;
  #pragma unroll
  for (int k = 0; k < 4; ++k) {
    int c = c0 + ty + 8 * k;
    tile[ty + 8 * k][tx] = x[((size_t)b * 320 + c) * 1024 + n0 + tx];
  }
  __syncthreads();
  #pragma unroll
  for (int k = 0; k < 4; ++k) {
    int n = n0 + ty + 8 * k;
    float v = tile[tx][ty + 8 * k];
    size_t idx = ((size_t)b * 1024 + n) * 320 + c0 + tx;
    node[idx] = v;
    nodebf[idx] = f2bf(v);
  }
}

__global__ __launch_bounds__(320) void k_svec(const float* __restrict__ da,
    const float* __restrict__ fw, const float* __restrict__ fb, float* __restrict__ sv) {
  __shared__ float ds[64];
  const int b = blockIdx.x, t = threadIdx.x;
  if (t < 64) {
    float a = 0.f;
    #pragma unroll
    for (int i = 0; i < 16; ++i) a += da[b * 1024 + i * 64 + t];
    ds[t] = a;
  }
  __syncthreads();
  if (t < 320) {
    float acc = 16.f * fb[t];
    #pragma unroll
    for (int e = 0; e < 64; ++e) acc = fmaf(ds[e], fw[t * 64 + e], acc);
    sv[b * 320 + t] = acc;
  }
}

// convert weights fp32->bf16; also zero qbf/kbf region (pads must be 0 each launch)
__global__ void k_wcvt(const float* __restrict__ a, int na,
                       const float* __restrict__ b, int nb,
                       const float* __restrict__ c, int nc,
                       unsigned short* __restrict__ out,
                       uint4* __restrict__ zbuf, int zn4) {
  int tot = na + nb + nc;
  for (int i = blockIdx.x * blockDim.x + threadIdx.x; i < tot; i += gridDim.x * blockDim.x) {
    float v = (i < na) ? a[i] : ((i < na + nb) ? b[i - na] : c[i - na - nb]);
    out[i] = f2bf(v);
  }
  const uint4 z = {0u, 0u, 0u, 0u};
  for (int i = blockIdx.x * blockDim.x + threadIdx.x; i < zn4; i += gridDim.x * blockDim.x)
    zbuf[i] = z;
}

// MFMA GEMM: C[2048, Ncols] = A[2048,320]bf16 @ W[Ncols,320]bf16^T (+bias)
// mode 0: p0 fp32 [row*320+col]
// mode 1: col<320 -> qe bf16 [B,N,320]; else ke bf16 [B,N,320]
// mode 2: q->p0 [B,H,N,64]bf16 (pads pre-zeroed); k->p1 same; v->p2 [B,H,48,1024]bf16
// mode 3: p0 fp32 [(b*320+col)*1024+n] via LDS transpose
__global__ __launch_bounds__(256, 4) void k_mgemm(
    const unsigned short* __restrict__ A, const unsigned short* __restrict__ W,
    const float* __restrict__ bias, void* p0, void* p1, void* p2, int mode) {
  __shared__ float smem[64 * 65];
  const int t = threadIdx.x, w = t >> 6, lane = t & 63;
  const int q16 = lane >> 4, l16 = lane & 15;
  const int rt = blockIdx.x * 64, jt = blockIdx.y * 64;
  f32x4 acc[4];
  #pragma unroll
  for (int i = 0; i < 4; ++i)
    #pragma unroll
    for (int j = 0; j < 4; ++j) acc[i][j] = 0.f;
  const unsigned short* ap = A + (size_t)(rt + 16 * w + l16) * 320 + q16 * 8;
  const unsigned short* wp = W + (size_t)(jt + l16) * 320 + q16 * 8;
  for (int kc = 0; kc < 10; ++kc) {
    bf8 af = *(const bf8*)(ap + kc * 32);
    #pragma unroll
    for (int ct = 0; ct < 4; ++ct) {
      bf8 bf = *(const bf8*)(wp + (size_t)ct * 16 * 320 + kc * 32);
      acc[ct] = mfma16(af, bf, acc[ct]);
    }
  }
  if (mode == 0 || mode == 1) {
    #pragma unroll
    for (int ct = 0; ct < 4; ++ct) {
      int col = jt + ct * 16 + l16;
      float bv = bias ? bias[col] : 0.f;
      #pragma unroll
      for (int r = 0; r < 4; ++r) {
        int row = rt + 16 * w + q16 * 4 + r;
        float v = acc[ct][r] + bv;
        if (mode == 0) {
          ((float*)p0)[(size_t)row * 320 + col] = v;
        } else {
          if (col < 320) ((unsigned short*)p0)[(size_t)row * 320 + col] = f2bf(v);
          else           ((unsigned short*)p1)[(size_t)row * 320 + col - 320] = f2bf(v);
        }
      }
    }
  } else if (mode == 2) {
    const int part = jt / 320;
    if (part < 2) {
      unsigned short* dst = (unsigned short*)(part == 0 ? p0 : p1);
      #pragma unroll
      for (int ct = 0; ct < 4; ++ct) {
        int col = jt + ct * 16 + l16;
        float bv = bias[col];
        int rem = col - part * 320;
        int h = rem / 40, d = rem % 40;
        #pragma unroll
        for (int r = 0; r < 4; ++r) {
          int row = rt + 16 * w + q16 * 4 + r;
          int b = row >> 10, n = row & 1023;
          dst[(((size_t)b * 8 + h) * 1024 + n) * 64 + d] = f2bf(acc[ct][r] + bv);
        }
      }
    } else {
      unsigned short* vt_t = (unsigned short*)smem;       // [64][72]
      #pragma unroll
      for (int ct = 0; ct < 4; ++ct) {
        int col = jt + ct * 16 + l16;
        float bv = bias[col];
        #pragma unroll
        for (int r = 0; r < 4; ++r)
          vt_t[(ct * 16 + l16) * 72 + 16 * w + q16 * 4 + r] = f2bf(acc[ct][r] + bv);
      }
      __syncthreads();
      const int cl = t >> 2, seg = t & 3;
      int rem = (jt - 640) + cl;
      int h = rem / 40, d = rem % 40;
      int b = rt >> 10, n = (rt & 1023) + seg * 16;
      const float4* lp = (const float4*)&vt_t[cl * 72 + seg * 16];
      float4 a0 = lp[0], a1 = lp[1];
      float4* gp = (float4*)((unsigned short*)p2 +
                             (((size_t)b * 8 + h) * 48 + d) * 1024 + n);
      gp[0] = a0; gp[1] = a1;
    }
  } else {
    #pragma unroll
    for (int ct = 0; ct < 4; ++ct) {
      int col = jt + ct * 16 + l16;
      float bv = bias[col];
      #pragma unroll
      for (int r = 0; r < 4; ++r)
        smem[(16 * w + q16 * 4 + r) * 65 + ct * 16 + l16] = acc[ct][r] + bv;
    }
    __syncthreads();
    const int cl = t >> 2, seg = t & 3;
    int b = rt >> 10, n = (rt & 1023) + seg * 16;
    float* orow = (float*)p0 + ((size_t)b * 320 + jt + cl) * 1024 + n;
    #pragma unroll
    for (int i2 = 0; i2 < 4; ++i2) {
      float4 vv;
      vv.x = smem[(seg * 16 + i2 * 4 + 0) * 65 + cl];
      vv.y = smem[(seg * 16 + i2 * 4 + 1) * 65 + cl];
      vv.z = smem[(seg * 16 + i2 * 4 + 2) * 65 + cl];
      vv.w = smem[(seg * 16 + i2 * 4 + 3) * 65 + cl];
      ((float4*)orow)[i2] = vv;
    }
  }
}

// Fused edge init: edge = softmax(qe @ ke^T * EDGE_SCALE) per row (max-free, safe).
__global__ __launch_bounds__(512, 2) void k_edge3(
    const unsigned short* __restrict__ qe, const unsigned short* __restrict__ ke,
    float* __restrict__ edge) {
  __shared__ float zred[8][16];
  const int t = threadIdx.x, w = t >> 6, lane = t & 63;
  const int q16 = lane >> 4, l16 = lane & 15;
  const int n0 = blockIdx.x * 16, b = blockIdx.y;
  const unsigned short* qp = qe + ((size_t)(b * 1024 + n0 + l16)) * 320 + q16 * 8;
  bf8 af[10];
  #pragma unroll
  for (int kc = 0; kc < 10; ++kc) af[kc] = *(const bf8*)(qp + kc * 32);
  f32x4 acc[8];
  #pragma unroll
  for (int i = 0; i < 8; ++i)
    #pragma unroll
    for (int j = 0; j < 4; ++j) acc[i][j] = 0.f;
  const unsigned short* kp = ke + ((size_t)(b * 1024 + w * 128 + l16)) * 320 + q16 * 8;
  #pragma unroll
  for (int mt = 0; mt < 8; ++mt) {
    const unsigned short* kpt = kp + (size_t)mt * 16 * 320;
    #pragma unroll
    for (int kc = 0; kc < 10; ++kc) {
      bf8 bf = *(const bf8*)(kpt + kc * 32);
      acc[mt] = mfma16(af[kc], bf, acc[mt]);
    }
  }
  float zp[4] = {0.f, 0.f, 0.f, 0.f};
  #pragma unroll
  for (int mt = 0; mt < 8; ++mt)
    #pragma unroll
    for (int r = 0; r < 4; ++r) {
      float e = __expf(acc[mt][r] * EDGE_SCALE);
      acc[mt][r] = e;
      zp[r] += e;
    }
  #pragma unroll
  for (int r = 0; r < 4; ++r)
    #pragma unroll
    for (int o = 1; o <= 8; o <<= 1) zp[r] += __shfl_xor(zp[r], o);
  if (l16 == 0) {
    #pragma unroll
    for (int r = 0; r < 4; ++r) zred[w][q16 * 4 + r] = zp[r];
  }
  __syncthreads();
  float inv[4];
  #pragma unroll
  for (int r = 0; r < 4; ++r) {
    float s = 0.f;
    #pragma unroll
    for (int ww = 0; ww < 8; ++ww) s += zred[ww][q16 * 4 + r];
    inv[r] = 1.f / s;
  }
  #pragma unroll
  for (int r = 0; r < 4; ++r) {
    float* ep = edge + ((size_t)(b * 1024 + n0 + q16 * 4 + r)) * 1024 + w * 128 + l16;
    #pragma unroll
    for (int mt = 0; mt < 8; ++mt) ep[mt * 16] = acc[mt][r] * inv[r];
  }
}

// y_bf16 = LN(diag*LN(node)*s + LN(node)) per row; wave = 1 row.
__global__ __launch_bounds__(256) void k_ln(const float* __restrict__ node,
    const float* __restrict__ edge, const float* __restrict__ sv,
    const float* __restrict__ g1, const float* __restrict__ b1,
    const float* __restrict__ g2, const float* __restrict__ b2,
    unsigned short* __restrict__ y) {
  const int w = threadIdx.x >> 6, lane = threadIdx.x & 63;
  const int row = blockIdx.x * 4 + w;
  const int b = row >> 10, n = row & 1023;
  const float* xr = node + (size_t)row * 320;
  float x[5];
  #pragma unroll
  for (int i = 0; i < 5; ++i) x[i] = xr[lane + 64 * i];
  float s = x[0] + x[1] + x[2] + x[3] + x[4];
  float mean = wave_sum(s) * (1.f / 320.f);
  float v = 0.f;
  #pragma unroll
  for (int i = 0; i < 5; ++i) { float d = x[i] - mean; v += d * d; }
  float rstd = rsqrtf(wave_sum(v) * (1.f / 320.f) + LN_EPS);
  float diag = edge[(size_t)row * 1024 + n];
  float n2[5];
  #pragma unroll
  for (int i = 0; i < 5; ++i) {
    int c = lane + 64 * i;
    float nt = (x[i] - mean) * rstd * g1[c] + b1[c];
    n2[i] = diag * nt * sv[b * 320 + c] + nt;
  }
  s = n2[0] + n2[1] + n2[2] + n2[3] + n2[4];
  float mean2 = wave_sum(s) * (1.f / 320.f);
  v = 0.f;
  #pragma unroll
  for (int i = 0; i < 5; ++i) { float d = n2[i] - mean2; v += d * d; }
  float rstd2 = rsqrtf(wave_sum(v) * (1.f / 320.f) + LN_EPS);
  unsigned short* yr = y + (size_t)row * 320;
  #pragma unroll
  for (int i = 0; i < 5; ++i) {
    int c = lane + 64 * i;
    yr[c] = f2bf((n2[i] - mean2) * rstd2 * g2[c] + b2[c]);
  }
}

// Attention scores + AV, 2 heads per block. Block = (16-row tile, hp, b), 256 thr.
// Wave w owns m-cols [256w, 256w+256). Max-free softmax (logits bounded).
// t = sum over both heads of rw_h*(a+s), written bf16 scatter to th[B,4,N,M].
__global__ __launch_bounds__(256, 2) void k_score2(
    const unsigned short* __restrict__ qbf, const unsigned short* __restrict__ kbf,
    const unsigned short* __restrict__ vtb, const float* __restrict__ edge,
    unsigned short* __restrict__ th, float* __restrict__ att,
    const float* __restrict__ ew, const float* __restrict__ eb,
    const float* __restrict__ rw) {
  __shared__ unsigned short a_lds[4][4][16][20];  // 10 KB, per-wave private
  __shared__ float ored[2][4][3][16][17];         // 26 KB
  __shared__ float zred[2][4][16];
  const int t = threadIdx.x, w = t >> 6, lane = t & 63;
  const int q16 = lane >> 4, l16 = lane & 15;
  const int n0 = blockIdx.x * 16, hp = blockIdx.y, b = blockIdx.z;
  float t_reg[16][4];
  #pragma unroll
  for (int tt = 0; tt < 16; ++tt)
    #pragma unroll
    for (int r = 0; r < 4; ++r) t_reg[tt][r] = 0.f;
  f32x4 oacc[2][3];
  #pragma unroll
  for (int hh = 0; hh < 2; ++hh)
    #pragma unroll
    for (int i = 0; i < 3; ++i)
      #pragma unroll
      for (int j = 0; j < 4; ++j) oacc[hh][i][j] = 0.f;
  const float* ep = edge + ((size_t)(b * 1024 + n0 + q16 * 4)) * 1024 + w * 256 + l16;
  #pragma unroll 1
  for (int hh = 0; hh < 2; ++hh) {
    const int h = hp * 2 + hh;
    const size_t bh = (size_t)b * 8 + h;
    const float ewh = ew[h], ebh = eb[h], rwh = rw[h];
    const unsigned short* qp = qbf + (bh * 1024 + n0 + l16) * 64 + q16 * 8;
    bf8 af0 = *(const bf8*)(qp);
    bf8 af1 = *(const bf8*)(qp + 32);
    f32x4 acc[16];
    #pragma unroll
    for (int i = 0; i < 16; ++i)
      #pragma unroll
      for (int j = 0; j < 4; ++j) acc[i][j] = 0.f;
    const unsigned short* kp = kbf + (bh * 1024 + (size_t)w * 256 + l16) * 64 + q16 * 8;
    #pragma unroll
    for (int tt = 0; tt < 16; ++tt) {
      const unsigned short* kpt = kp + (size_t)tt * 16 * 64;
      bf8 b0 = *(const bf8*)(kpt);
      bf8 b1 = *(const bf8*)(kpt + 32);
      acc[tt] = mfma16(af0, b0, acc[tt]);
      acc[tt] = mfma16(af1, b1, acc[tt]);
    }
    // bias + exp-sum (max-free)
    float zp[4] = {0.f, 0.f, 0.f, 0.f};
    #pragma unroll
    for (int tt = 0; tt < 16; ++tt)
      #pragma unroll
      for (int r = 0; r < 4; ++r) {
        float ev = ep[(size_t)r * 1024 + tt * 16];
        float s = fmaf(acc[tt][r], ATT_SCALE, fmaf(ev, ewh, ebh));
        acc[tt][r] = s;
        zp[r] += __expf(s);
      }
    #pragma unroll
    for (int r = 0; r < 4; ++r)
      #pragma unroll
      for (int o = 1; o <= 8; o <<= 1) zp[r] += __shfl_xor(zp[r], o);
    if (l16 == 0) {
      #pragma unroll
      for (int r = 0; r < 4; ++r) zred[hh][w][q16 * 4 + r] = zp[r];
    }
    __syncthreads();
    float invZ[4];
    #pragma unroll
    for (int r = 0; r < 4; ++r)
      invZ[r] = 1.f / (zred[hh][0][q16 * 4 + r] + zred[hh][1][q16 * 4 + r] +
                       zred[hh][2][q16 * 4 + r] + zred[hh][3][q16 * 4 + r]);
    // grouped: a->LDS + t accumulate + AV MFMA (per-wave private)
    #pragma unroll
    for (int g = 0; g < 4; ++g) {
      #pragma unroll
      for (int ti = 0; ti < 4; ++ti) {
        int tt = g * 4 + ti;
        #pragma unroll
        for (int r = 0; r < 4; ++r) {
          float s = acc[tt][r];
          float e = __expf(s);
          a_lds[w][ti][q16 * 4 + r][l16] = f2bf(e * invZ[r]);
          t_reg[tt][r] = fmaf(rwh, fmaf(e, invZ[r], s), t_reg[tt][r]);
        }
      }
      #pragma unroll
      for (int kk = 0; kk < 2; ++kk) {
        const unsigned short* ap2 = &a_lds[w][kk * 2 + (q16 >> 1)][l16][(q16 & 1) * 8];
        short4 lo = *(const short4*)(ap2);
        short4 hi = *(const short4*)(ap2 + 4);
        bf8 afv = {lo.x, lo.y, lo.z, lo.w, hi.x, hi.y, hi.z, hi.w};
        int kc = w * 8 + g * 2 + kk;
        const unsigned short* vp = vtb + (bh * 48 + l16) * 1024 + (size_t)kc * 32 + q16 * 8;
        #pragma unroll
        for (int nt = 0; nt < 3; ++nt) {
          bf8 bfv = *(const bf8*)(vp + (size_t)nt * 16 * 1024);
          oacc[hh][nt] = mfma16(afv, bfv, oacc[hh][nt]);
        }
      }
    }
  }
  // th scatter (bf16, R3-measured pattern)
  {
    unsigned short* tp = th + (((size_t)(b * 4 + hp)) * 1024 + n0 + q16 * 4) * 1024
                         + w * 256 + l16;
    #pragma unroll
    for (int tt = 0; tt < 16; ++tt)
      #pragma unroll
      for (int r = 0; r < 4; ++r)
        tp[(size_t)r * 1024 + tt * 16] = f2bf(t_reg[tt][r]);
  }
  // att: cross-wave AV reduce for both heads
  #pragma unroll
  for (int hh = 0; hh < 2; ++hh)
    #pragma unroll
    for (int nt = 0; nt < 3; ++nt)
      #pragma unroll
      for (int r = 0; r < 4; ++r) ored[hh][w][nt][q16 * 4 + r][l16] = oacc[hh][nt][r];
  __syncthreads();
  #pragma unroll
  for (int hh = 0; hh < 2; ++hh) {
    #pragma unroll
    for (int k = 0; k < 3; ++k) {
      int o = k * 256 + t;
      int nt = o >> 8, row = (o >> 4) & 15, col = o & 15;
      int dim = nt * 16 + col;
      float sum = ored[hh][0][nt][row][col] + ored[hh][1][nt][row][col] +
                  ored[hh][2][nt][row][col] + ored[hh][3][nt][row][col];
      if (dim < 40)
        att[((size_t)b * 1024 + n0 + row) * 320 + (hp * 2 + hh) * 40 + dim] = sum;
    }
  }
}

// reduce th over 4 hp-slices -> t; edge += t; ws-softmax -> wsum; attbf = att + wsum
__global__ __launch_bounds__(256) void k_wsum(
    const unsigned short* __restrict__ th, float* __restrict__ edge,
    const float* __restrict__ att, unsigned short* __restrict__ attbf,
    const float* __restrict__ rb) {
  const int w = threadIdx.x >> 6, lane = threadIdx.x & 63;
  const int row = blockIdx.x * 4 + w;
  const int b = row >> 10, n = row & 1023;
  const float rbv = rb[0];
  float tv[16];
  #pragma unroll
  for (int i = 0; i < 16; ++i) tv[i] = rbv;
  #pragma unroll 1
  for (int hp = 0; hp < 4; ++hp) {
    const unsigned short* tph = th + (((size_t)b * 4 + hp) * 1024 + n) * 1024 + lane * 4;
    #pragma unroll
    for (int seg = 0; seg < 4; ++seg) {
      ushort4 u = *(const ushort4*)(tph + seg * 256);
      tv[seg * 4 + 0] += bf2f(u.x);
      tv[seg * 4 + 1] += bf2f(u.y);
      tv[seg * 4 + 2] += bf2f(u.z);
      tv[seg * 4 + 3] += bf2f(u.w);
    }
  }
  float4* erp = (float4*)(edge + ((size_t)b * 1024 + n) * 1024) + lane;
  #pragma unroll
  for (int seg = 0; seg < 4; ++seg) {
    float4 e = erp[seg * 64];
    e.x += tv[seg * 4 + 0]; e.y += tv[seg * 4 + 1];
    e.z += tv[seg * 4 + 2]; e.w += tv[seg * 4 + 3];
    erp[seg * 64] = e;
  }
  float mx = -3.4e38f;
  #pragma unroll
  for (int i = 0; i < 16; ++i) mx = fmaxf(mx, tv[i]);
  mx = wave_max(mx);
  float s = 0.f, num = 0.f;
  #pragma unroll
  for (int i = 0; i < 16; ++i) {
    float e = __expf(tv[i] - mx);
    s += e; num += e * tv[i];
  }
  s = wave_sum(s); num = wave_sum(num);
  const float wsum = num / s;
  const float* ar = att + (size_t)row * 320;
  unsigned short* ao = attbf + (size_t)row * 320;
  #pragma unroll
  for (int i = 0; i < 5; ++i) {
    int c = lane + 64 * i;
    ao[c] = f2bf(ar[c] + wsum);
  }
}

extern "C" void kernel_launch(void* const* d_in, const int* in_sizes, int n_in,
                              void* d_out, int out_size, void* d_ws, size_t ws_size,
                              hipStream_t stream) {
  const float* x      = (const float*)d_in[0];
  const float* da     = (const float*)d_in[1];
  const float* qk_w   = (const float*)d_in[2];
  const float* fcp_w  = (const float*)d_in[3];
  const float* fcp_b  = (const float*)d_in[4];
  const float* ln1_g  = (const float*)d_in[5];
  const float* ln1_b  = (const float*)d_in[6];
  const float* gln_g  = (const float*)d_in[7];
  const float* gln_b  = (const float*)d_in[8];
  const float* qkv_w  = (const float*)d_in[9];
  const float* qkv_b  = (const float*)d_in[10];
  const float* proj_w = (const float*)d_in[11];
  const float* proj_b = (const float*)d_in[12];
  const float* exp_w  = (const float*)d_in[13];
  const float* exp_b  = (const float*)d_in[14];
  const float* red_w  = (const float*)d_in[15];
  const float* red_b  = (const float*)d_in[16];
  float* ws = (float*)d_ws;
  float* node  = ws + 0;                                   // 655360
  unsigned short* ybf   = (unsigned short*)(ws + 655360);  // 327680 fl
  float* attb  = ws + 983040;                              // 655360
  unsigned short* attbf = (unsigned short*)(ws + 1638400); // 327680 fl
  float* edge  = ws + 1966080;                             // 2097152
  float* svec  = ws + 4063232;                             // 640
  unsigned short* nodebf = (unsigned short*)(ws + 4063872);// 327680 fl
  unsigned short* qe   = (unsigned short*)(ws + 4391552);  // 327680 fl
  unsigned short* ke   = (unsigned short*)(ws + 4719232);  // 327680 fl
  unsigned short* qbf  = (unsigned short*)(ws + 5046912);  // 524288 fl
  unsigned short* kbf  = (unsigned short*)(ws + 5571200);  // 524288 fl
  unsigned short* vtb  = (unsigned short*)(ws + 6095488);  // 393216 fl
  unsigned short* wbf  = (unsigned short*)(ws + 6488704);  // 512000 fl
  unsigned short* th   = (unsigned short*)(ws + 7000704);  // 4194304 fl
  float* out = (float*)d_out;
  unsigned short* qk_wb   = wbf;
  unsigned short* qkv_wb  = wbf + 204800;
  unsigned short* proj_wb = wbf + 819200;

  hipLaunchKernelGGL(k_trans, dim3(32, 10, 2), dim3(256), 0, stream, x, node, nodebf);
  hipLaunchKernelGGL(k_svec, dim3(2), dim3(320), 0, stream, da, fcp_w, fcp_b, svec);
  hipLaunchKernelGGL(k_wcvt, dim3(512), dim3(256), 0, stream,
                     qk_w, 204800, qkv_w, 614400, proj_w, 204800, wbf,
                     (uint4*)qbf, 262144);
  hipLaunchKernelGGL(k_mgemm, dim3(32, 10), dim3(256), 0, stream,
                     nodebf, qk_wb, (const float*)nullptr, qe, ke, (void*)nullptr, 1);
  hipLaunchKernelGGL(k_edge3, dim3(64, 2), dim3(512), 0, stream, qe, ke, edge);
  for (int l = 0; l < 2; ++l) {
    hipLaunchKernelGGL(k_ln, dim3(512), dim3(256), 0, stream, node, edge, svec,
                       ln1_g + l * 320, ln1_b + l * 320, gln_g + l * 320, gln_b + l * 320, ybf);
    hipLaunchKernelGGL(k_mgemm, dim3(32, 15), dim3(256), 0, stream,
                       ybf, qkv_wb + (size_t)l * 307200, qkv_b + l * 960, qbf, kbf, vtb, 2);
    hipLaunchKernelGGL(k_score2, dim3(64, 4, 2), dim3(256), 0, stream,
                       qbf, kbf, vtb, edge, th, attb,
                       exp_w + l * 8, exp_b + l * 8, red_w + l * 8);
    hipLaunchKernelGGL(k_wsum, dim3(512), dim3(256), 0, stream,
                       th, edge, attb, attbf, red_b + l);
    if (l == 0)
      hipLaunchKernelGGL(k_mgemm, dim3(32, 5), dim3(256), 0, stream,
                         attbf, proj_wb, proj_b, node, (void*)nullptr, (void*)nullptr, 0);
    else
      hipLaunchKernelGGL(k_mgemm, dim3(32, 5), dim3(256), 0, stream,
                         attbf, proj_wb + 102400, proj_b + 320, out,
                         (void*)nullptr, (void*)nullptr, 3);
  }
}

// Round 7
// 294.068 us; speedup vs baseline: 1.2699x; 1.1588x over previous
//
#include <hip/hip_runtime.h>
#include <math.h>

#define EDGE_SCALE 0.17677669529663687f   // 32^-0.5
#define ATT_SCALE  0.15811388300841897f   // 40^-0.5
#define LN_EPS 1e-5f

typedef __attribute__((ext_vector_type(8))) short bf8;
typedef __attribute__((ext_vector_type(4))) float f32x4;

__device__ __forceinline__ f32x4 mfma16(bf8 a, bf8 b, f32x4 c) {
  return __builtin_amdgcn_mfma_f32_16x16x32_bf16(a, b, c, 0, 0, 0);
}
__device__ __forceinline__ unsigned short f2bf(float f) {
  union { float f; unsigned u; } v; v.f = f;
  unsigned r = v.u + 0x7FFF + ((v.u >> 16) & 1);
  return (unsigned short)(r >> 16);
}
__device__ __forceinline__ float bf2f(unsigned short h) {
  union { unsigned u; float f; } v; v.u = ((unsigned)h) << 16;
  return v.f;
}
__device__ __forceinline__ float wave_max(float v) {
  #pragma unroll
  for (int o = 32; o > 0; o >>= 1) v = fmaxf(v, __shfl_xor(v, o));
  return v;
}
__device__ __forceinline__ float wave_sum(float v) {
  #pragma unroll
  for (int o = 32; o > 0; o >>= 1) v += __shfl_xor(v, o);
  return v;
}

// node[b,n,c] = x[b,c,n]; also bf16 copy
__global__ __launch_bounds__(256) void k_trans(const float* __restrict__ x,
    float* __restrict__ node, unsigned short* __restrict__ nodebf) {
  __shared__ float tile[32][33];
  const int b = blockIdx.z;
  const int n0 = blockIdx.x * 32, c0 = blockIdx.y * 32;
  const int tx = threadIdx.x & 31, ty = threadIdx.x >> 5;
  #pragma unroll
  for (int k = 0; k < 4; ++k) {
    int c = c0 + ty + 8 * k;
    tile[ty + 8 * k][tx] = x[((size_t)b * 320 + c) * 1024 + n0 + tx];
  }
  __syncthreads();
  #pragma unroll
  for (int k = 0; k < 4; ++k) {
    int n = n0 + ty + 8 * k;
    float v = tile[tx][ty + 8 * k];
    size_t idx = ((size_t)b * 1024 + n) * 320 + c0 + tx;
    node[idx] = v;
    nodebf[idx] = f2bf(v);
  }
}

__global__ __launch_bounds__(320) void k_svec(const float* __restrict__ da,
    const float* __restrict__ fw, const float* __restrict__ fb, float* __restrict__ sv) {
  __shared__ float ds[64];
  const int b = blockIdx.x, t = threadIdx.x;
  if (t < 64) {
    float a = 0.f;
    #pragma unroll
    for (int i = 0; i < 16; ++i) a += da[b * 1024 + i * 64 + t];
    ds[t] = a;
  }
  __syncthreads();
  if (t < 320) {
    float acc = 16.f * fb[t];
    #pragma unroll
    for (int e = 0; e < 64; ++e) acc = fmaf(ds[e], fw[t * 64 + e], acc);
    sv[b * 320 + t] = acc;
  }
}

// convert weights fp32->bf16; also zero qbf/kbf region (pads must be 0 each launch)
__global__ void k_wcvt(const float* __restrict__ a, int na,
                       const float* __restrict__ b, int nb,
                       const float* __restrict__ c, int nc,
                       unsigned short* __restrict__ out,
                       uint4* __restrict__ zbuf, int zn4) {
  int tot = na + nb + nc;
  for (int i = blockIdx.x * blockDim.x + threadIdx.x; i < tot; i += gridDim.x * blockDim.x) {
    float v = (i < na) ? a[i] : ((i < na + nb) ? b[i - na] : c[i - na - nb]);
    out[i] = f2bf(v);
  }
  const uint4 z = {0u, 0u, 0u, 0u};
  for (int i = blockIdx.x * blockDim.x + threadIdx.x; i < zn4; i += gridDim.x * blockDim.x)
    zbuf[i] = z;
}

// MFMA GEMM: C[2048, Ncols] = A[2048,320]bf16 @ W[Ncols,320]bf16^T (+bias)
// mode 0: p0 fp32 [row*320+col]
// mode 1: col<320 -> qe bf16 [B,N,320]; else ke bf16 [B,N,320]
// mode 2: q->p0 [B,H,N,64]bf16 (pads pre-zeroed); k->p1 same; v->p2 [B,H,48,1024]bf16
// mode 3: p0 fp32 [(b*320+col)*1024+n] via LDS transpose
__global__ __launch_bounds__(256, 4) void k_mgemm(
    const unsigned short* __restrict__ A, const unsigned short* __restrict__ W,
    const float* __restrict__ bias, void* p0, void* p1, void* p2, int mode) {
  __shared__ float smem[64 * 65];
  const int t = threadIdx.x, w = t >> 6, lane = t & 63;
  const int q16 = lane >> 4, l16 = lane & 15;
  const int rt = blockIdx.x * 64, jt = blockIdx.y * 64;
  f32x4 acc[4];
  #pragma unroll
  for (int i = 0; i < 4; ++i)
    #pragma unroll
    for (int j = 0; j < 4; ++j) acc[i][j] = 0.f;
  const unsigned short* ap = A + (size_t)(rt + 16 * w + l16) * 320 + q16 * 8;
  const unsigned short* wp = W + (size_t)(jt + l16) * 320 + q16 * 8;
  for (int kc = 0; kc < 10; ++kc) {
    bf8 af = *(const bf8*)(ap + kc * 32);
    #pragma unroll
    for (int ct = 0; ct < 4; ++ct) {
      bf8 bf = *(const bf8*)(wp + (size_t)ct * 16 * 320 + kc * 32);
      acc[ct] = mfma16(af, bf, acc[ct]);
    }
  }
  if (mode == 0 || mode == 1) {
    #pragma unroll
    for (int ct = 0; ct < 4; ++ct) {
      int col = jt + ct * 16 + l16;
      float bv = bias ? bias[col] : 0.f;
      #pragma unroll
      for (int r = 0; r < 4; ++r) {
        int row = rt + 16 * w + q16 * 4 + r;
        float v = acc[ct][r] + bv;
        if (mode == 0) {
          ((float*)p0)[(size_t)row * 320 + col] = v;
        } else {
          if (col < 320) ((unsigned short*)p0)[(size_t)row * 320 + col] = f2bf(v);
          else           ((unsigned short*)p1)[(size_t)row * 320 + col - 320] = f2bf(v);
        }
      }
    }
  } else if (mode == 2) {
    const int part = jt / 320;
    if (part < 2) {
      unsigned short* dst = (unsigned short*)(part == 0 ? p0 : p1);
      #pragma unroll
      for (int ct = 0; ct < 4; ++ct) {
        int col = jt + ct * 16 + l16;
        float bv = bias[col];
        int rem = col - part * 320;
        int h = rem / 40, d = rem % 40;
        #pragma unroll
        for (int r = 0; r < 4; ++r) {
          int row = rt + 16 * w + q16 * 4 + r;
          int b = row >> 10, n = row & 1023;
          dst[(((size_t)b * 8 + h) * 1024 + n) * 64 + d] = f2bf(acc[ct][r] + bv);
        }
      }
    } else {
      unsigned short* vt_t = (unsigned short*)smem;       // [64][72]
      #pragma unroll
      for (int ct = 0; ct < 4; ++ct) {
        int col = jt + ct * 16 + l16;
        float bv = bias[col];
        #pragma unroll
        for (int r = 0; r < 4; ++r)
          vt_t[(ct * 16 + l16) * 72 + 16 * w + q16 * 4 + r] = f2bf(acc[ct][r] + bv);
      }
      __syncthreads();
      const int cl = t >> 2, seg = t & 3;
      int rem = (jt - 640) + cl;
      int h = rem / 40, d = rem % 40;
      int b = rt >> 10, n = (rt & 1023) + seg * 16;
      const float4* lp = (const float4*)&vt_t[cl * 72 + seg * 16];
      float4 a0 = lp[0], a1 = lp[1];
      float4* gp = (float4*)((unsigned short*)p2 +
                             (((size_t)b * 8 + h) * 48 + d) * 1024 + n);
      gp[0] = a0; gp[1] = a1;
    }
  } else {
    #pragma unroll
    for (int ct = 0; ct < 4; ++ct) {
      int col = jt + ct * 16 + l16;
      float bv = bias[col];
      #pragma unroll
      for (int r = 0; r < 4; ++r)
        smem[(16 * w + q16 * 4 + r) * 65 + ct * 16 + l16] = acc[ct][r] + bv;
    }
    __syncthreads();
    const int cl = t >> 2, seg = t & 3;
    int b = rt >> 10, n = (rt & 1023) + seg * 16;
    float* orow = (float*)p0 + ((size_t)b * 320 + jt + cl) * 1024 + n;
    #pragma unroll
    for (int i2 = 0; i2 < 4; ++i2) {
      float4 vv;
      vv.x = smem[(seg * 16 + i2 * 4 + 0) * 65 + cl];
      vv.y = smem[(seg * 16 + i2 * 4 + 1) * 65 + cl];
      vv.z = smem[(seg * 16 + i2 * 4 + 2) * 65 + cl];
      vv.w = smem[(seg * 16 + i2 * 4 + 3) * 65 + cl];
      ((float4*)orow)[i2] = vv;
    }
  }
}

// Fused edge init: edge = softmax(qe @ ke^T * EDGE_SCALE) per row (max-free, safe).
__global__ __launch_bounds__(512, 2) void k_edge3(
    const unsigned short* __restrict__ qe, const unsigned short* __restrict__ ke,
    float* __restrict__ edge) {
  __shared__ float zred[8][16];
  const int t = threadIdx.x, w = t >> 6, lane = t & 63;
  const int q16 = lane >> 4, l16 = lane & 15;
  const int n0 = blockIdx.x * 16, b = blockIdx.y;
  const unsigned short* qp = qe + ((size_t)(b * 1024 + n0 + l16)) * 320 + q16 * 8;
  bf8 af[10];
  #pragma unroll
  for (int kc = 0; kc < 10; ++kc) af[kc] = *(const bf8*)(qp + kc * 32);
  f32x4 acc[8];
  #pragma unroll
  for (int i = 0; i < 8; ++i)
    #pragma unroll
    for (int j = 0; j < 4; ++j) acc[i][j] = 0.f;
  const unsigned short* kp = ke + ((size_t)(b * 1024 + w * 128 + l16)) * 320 + q16 * 8;
  #pragma unroll
  for (int mt = 0; mt < 8; ++mt) {
    const unsigned short* kpt = kp + (size_t)mt * 16 * 320;
    #pragma unroll
    for (int kc = 0; kc < 10; ++kc) {
      bf8 bf = *(const bf8*)(kpt + kc * 32);
      acc[mt] = mfma16(af[kc], bf, acc[mt]);
    }
  }
  float zp[4] = {0.f, 0.f, 0.f, 0.f};
  #pragma unroll
  for (int mt = 0; mt < 8; ++mt)
    #pragma unroll
    for (int r = 0; r < 4; ++r) {
      float e = __expf(acc[mt][r] * EDGE_SCALE);
      acc[mt][r] = e;
      zp[r] += e;
    }
  #pragma unroll
  for (int r = 0; r < 4; ++r)
    #pragma unroll
    for (int o = 1; o <= 8; o <<= 1) zp[r] += __shfl_xor(zp[r], o);
  if (l16 == 0) {
    #pragma unroll
    for (int r = 0; r < 4; ++r) zred[w][q16 * 4 + r] = zp[r];
  }
  __syncthreads();
  float inv[4];
  #pragma unroll
  for (int r = 0; r < 4; ++r) {
    float s = 0.f;
    #pragma unroll
    for (int ww = 0; ww < 8; ++ww) s += zred[ww][q16 * 4 + r];
    inv[r] = 1.f / s;
  }
  #pragma unroll
  for (int r = 0; r < 4; ++r) {
    float* ep = edge + ((size_t)(b * 1024 + n0 + q16 * 4 + r)) * 1024 + w * 128 + l16;
    #pragma unroll
    for (int mt = 0; mt < 8; ++mt) ep[mt * 16] = acc[mt][r] * inv[r];
  }
}

// y_bf16 = LN(diag*LN(node)*s + LN(node)) per row; wave = 1 row.
__global__ __launch_bounds__(256) void k_ln(const float* __restrict__ node,
    const float* __restrict__ edge, const float* __restrict__ sv,
    const float* __restrict__ g1, const float* __restrict__ b1,
    const float* __restrict__ g2, const float* __restrict__ b2,
    unsigned short* __restrict__ y) {
  const int w = threadIdx.x >> 6, lane = threadIdx.x & 63;
  const int row = blockIdx.x * 4 + w;
  const int b = row >> 10, n = row & 1023;
  const float* xr = node + (size_t)row * 320;
  float x[5];
  #pragma unroll
  for (int i = 0; i < 5; ++i) x[i] = xr[lane + 64 * i];
  float s = x[0] + x[1] + x[2] + x[3] + x[4];
  float mean = wave_sum(s) * (1.f / 320.f);
  float v = 0.f;
  #pragma unroll
  for (int i = 0; i < 5; ++i) { float d = x[i] - mean; v += d * d; }
  float rstd = rsqrtf(wave_sum(v) * (1.f / 320.f) + LN_EPS);
  float diag = edge[(size_t)row * 1024 + n];
  float n2[5];
  #pragma unroll
  for (int i = 0; i < 5; ++i) {
    int c = lane + 64 * i;
    float nt = (x[i] - mean) * rstd * g1[c] + b1[c];
    n2[i] = diag * nt * sv[b * 320 + c] + nt;
  }
  s = n2[0] + n2[1] + n2[2] + n2[3] + n2[4];
  float mean2 = wave_sum(s) * (1.f / 320.f);
  v = 0.f;
  #pragma unroll
  for (int i = 0; i < 5; ++i) { float d = n2[i] - mean2; v += d * d; }
  float rstd2 = rsqrtf(wave_sum(v) * (1.f / 320.f) + LN_EPS);
  unsigned short* yr = y + (size_t)row * 320;
  #pragma unroll
  for (int i = 0; i < 5; ++i) {
    int c = lane + 64 * i;
    yr[c] = f2bf((n2[i] - mean2) * rstd2 * g2[c] + b2[c]);
  }
}

// Attention scores + AV per (b, h, 16-row tile). 1 head/block (R3 shape).
// Max-free softmax (bounded logits); grouped a_lds; th bf16 direct scatter.
__global__ __launch_bounds__(256, 4) void k_score3(
    const unsigned short* __restrict__ qbf, const unsigned short* __restrict__ kbf,
    const unsigned short* __restrict__ vtb, const float* __restrict__ edge,
    unsigned short* __restrict__ th, float* __restrict__ att,
    const float* __restrict__ ew, const float* __restrict__ eb,
    const float* __restrict__ rw) {
  __shared__ unsigned short a_lds[4][4][16][20];  // 10 KB per-wave private
  __shared__ float ored[4][3][16][17];            // 13 KB
  __shared__ float zred[4][16];
  const int t = threadIdx.x, w = t >> 6, lane = t & 63;
  const int q16 = lane >> 4, l16 = lane & 15;
  const int n0 = blockIdx.x * 16, h = blockIdx.y, b = blockIdx.z;
  const size_t bh = (size_t)b * 8 + h;
  const unsigned short* qp = qbf + (bh * 1024 + n0 + l16) * 64 + q16 * 8;
  bf8 af0 = *(const bf8*)(qp);
  bf8 af1 = *(const bf8*)(qp + 32);
  f32x4 acc[16];
  #pragma unroll
  for (int i = 0; i < 16; ++i)
    #pragma unroll
    for (int j = 0; j < 4; ++j) acc[i][j] = 0.f;
  const unsigned short* kp = kbf + (bh * 1024 + (size_t)w * 256 + l16) * 64 + q16 * 8;
  #pragma unroll
  for (int tt = 0; tt < 16; ++tt) {
    const unsigned short* kpt = kp + (size_t)tt * 16 * 64;
    bf8 b0 = *(const bf8*)(kpt);
    bf8 b1 = *(const bf8*)(kpt + 32);
    acc[tt] = mfma16(af0, b0, acc[tt]);
    acc[tt] = mfma16(af1, b1, acc[tt]);
  }
  // bias + exp partial-Z (max-free: logits bounded, fp32-safe)
  const float ewh = ew[h], ebh = eb[h], rwh = rw[h];
  const float* ep = edge + ((size_t)b * 1024 + n0 + q16 * 4) * 1024 + w * 256 + l16;
  float zp[4] = {0.f, 0.f, 0.f, 0.f};
  #pragma unroll
  for (int tt = 0; tt < 16; ++tt)
    #pragma unroll
    for (int r = 0; r < 4; ++r) {
      float ev = ep[(size_t)r * 1024 + tt * 16];
      float s = fmaf(acc[tt][r], ATT_SCALE, fmaf(ev, ewh, ebh));
      acc[tt][r] = s;
      zp[r] += __expf(s);
    }
  #pragma unroll
  for (int r = 0; r < 4; ++r)
    #pragma unroll
    for (int o = 1; o <= 8; o <<= 1) zp[r] += __shfl_xor(zp[r], o);
  if (l16 == 0) {
    #pragma unroll
    for (int r = 0; r < 4; ++r) zred[w][q16 * 4 + r] = zp[r];
  }
  __syncthreads();
  float invZ[4];
  #pragma unroll
  for (int r = 0; r < 4; ++r)
    invZ[r] = 1.f / (zred[0][q16 * 4 + r] + zred[1][q16 * 4 + r] +
                     zred[2][q16 * 4 + r] + zred[3][q16 * 4 + r]);
  // grouped: a->LDS + th scatter + AV MFMA (per-wave private, no barrier)
  f32x4 oacc[3];
  #pragma unroll
  for (int i = 0; i < 3; ++i)
    #pragma unroll
    for (int j = 0; j < 4; ++j) oacc[i][j] = 0.f;
  unsigned short* tp = th + (bh * 1024 + n0 + q16 * 4) * 1024 + w * 256 + l16;
  #pragma unroll
  for (int g = 0; g < 4; ++g) {
    #pragma unroll
    for (int ti = 0; ti < 4; ++ti) {
      int tt = g * 4 + ti;
      #pragma unroll
      for (int r = 0; r < 4; ++r) {
        float s = acc[tt][r];
        float e = __expf(s);
        float a = e * invZ[r];
        a_lds[w][ti][q16 * 4 + r][l16] = f2bf(a);
        tp[(size_t)r * 1024 + tt * 16] = f2bf(rwh * (a + s));
      }
    }
    #pragma unroll
    for (int kk = 0; kk < 2; ++kk) {
      const unsigned short* ap2 = &a_lds[w][kk * 2 + (q16 >> 1)][l16][(q16 & 1) * 8];
      short4 lo = *(const short4*)(ap2);
      short4 hi = *(const short4*)(ap2 + 4);
      bf8 afv = {lo.x, lo.y, lo.z, lo.w, hi.x, hi.y, hi.z, hi.w};
      int kc = w * 8 + g * 2 + kk;
      const unsigned short* vp = vtb + (bh * 48 + l16) * 1024 + (size_t)kc * 32 + q16 * 8;
      #pragma unroll
      for (int nt = 0; nt < 3; ++nt) {
        bf8 bfv = *(const bf8*)(vp + (size_t)nt * 16 * 1024);
        oacc[nt] = mfma16(afv, bfv, oacc[nt]);
      }
    }
  }
  #pragma unroll
  for (int nt = 0; nt < 3; ++nt)
    #pragma unroll
    for (int r = 0; r < 4; ++r) ored[w][nt][q16 * 4 + r][l16] = oacc[nt][r];
  __syncthreads();
  #pragma unroll
  for (int k = 0; k < 3; ++k) {
    int o = k * 256 + t;
    int nt = o >> 8, row = (o >> 4) & 15, col = o & 15;
    int dim = nt * 16 + col;
    float sum = ored[0][nt][row][col] + ored[1][nt][row][col] +
                ored[2][nt][row][col] + ored[3][nt][row][col];
    if (dim < 40)
      att[((size_t)b * 1024 + n0 + row) * 320 + h * 40 + dim] = sum;
  }
}

// reduce th over 8 head slices -> t; edge += t; ws-softmax -> wsum; attbf = att + wsum
__global__ __launch_bounds__(256) void k_wsum(
    const unsigned short* __restrict__ th, float* __restrict__ edge,
    const float* __restrict__ att, unsigned short* __restrict__ attbf,
    const float* __restrict__ rb) {
  const int w = threadIdx.x >> 6, lane = threadIdx.x & 63;
  const int row = blockIdx.x * 4 + w;
  const int b = row >> 10, n = row & 1023;
  const float rbv = rb[0];
  float tv[16];
  #pragma unroll
  for (int i = 0; i < 16; ++i) tv[i] = rbv;
  #pragma unroll 1
  for (int h = 0; h < 8; ++h) {
    const unsigned short* tph = th + (((size_t)b * 8 + h) * 1024 + n) * 1024 + lane * 4;
    #pragma unroll
    for (int seg = 0; seg < 4; ++seg) {
      ushort4 u = *(const ushort4*)(tph + seg * 256);
      tv[seg * 4 + 0] += bf2f(u.x);
      tv[seg * 4 + 1] += bf2f(u.y);
      tv[seg * 4 + 2] += bf2f(u.z);
      tv[seg * 4 + 3] += bf2f(u.w);
    }
  }
  float4* erp = (float4*)(edge + ((size_t)b * 1024 + n) * 1024) + lane;
  #pragma unroll
  for (int seg = 0; seg < 4; ++seg) {
    float4 e = erp[seg * 64];
    e.x += tv[seg * 4 + 0]; e.y += tv[seg * 4 + 1];
    e.z += tv[seg * 4 + 2]; e.w += tv[seg * 4 + 3];
    erp[seg * 64] = e;
  }
  float mx = -3.4e38f;
  #pragma unroll
  for (int i = 0; i < 16; ++i) mx = fmaxf(mx, tv[i]);
  mx = wave_max(mx);
  float s = 0.f, num = 0.f;
  #pragma unroll
  for (int i = 0; i < 16; ++i) {
    float e = __expf(tv[i] - mx);
    s += e; num += e * tv[i];
  }
  s = wave_sum(s); num = wave_sum(num);
  const float wsum = num / s;
  const float* ar = att + (size_t)row * 320;
  unsigned short* ao = attbf + (size_t)row * 320;
  #pragma unroll
  for (int i = 0; i < 5; ++i) {
    int c = lane + 64 * i;
    ao[c] = f2bf(ar[c] + wsum);
  }
}

extern "C" void kernel_launch(void* const* d_in, const int* in_sizes, int n_in,
                              void* d_out, int out_size, void* d_ws, size_t ws_size,
                              hipStream_t stream) {
  const float* x      = (const float*)d_in[0];
  const float* da     = (const float*)d_in[1];
  const float* qk_w   = (const float*)d_in[2];
  const float* fcp_w  = (const float*)d_in[3];
  const float* fcp_b  = (const float*)d_in[4];
  const float* ln1_g  = (const float*)d_in[5];
  const float* ln1_b  = (const float*)d_in[6];
  const float* gln_g  = (const float*)d_in[7];
  const float* gln_b  = (const float*)d_in[8];
  const float* qkv_w  = (const float*)d_in[9];
  const float* qkv_b  = (const float*)d_in[10];
  const float* proj_w = (const float*)d_in[11];
  const float* proj_b = (const float*)d_in[12];
  const float* exp_w  = (const float*)d_in[13];
  const float* exp_b  = (const float*)d_in[14];
  const float* red_w  = (const float*)d_in[15];
  const float* red_b  = (const float*)d_in[16];
  float* ws = (float*)d_ws;
  float* node  = ws + 0;                                   // 655360
  unsigned short* ybf   = (unsigned short*)(ws + 655360);  // 327680 fl
  float* attb  = ws + 983040;                              // 655360
  unsigned short* attbf = (unsigned short*)(ws + 1638400); // 327680 fl
  float* edge  = ws + 1966080;                             // 2097152
  float* svec  = ws + 4063232;                             // 640
  unsigned short* nodebf = (unsigned short*)(ws + 4063872);// 327680 fl
  unsigned short* qe   = (unsigned short*)(ws + 4391552);  // 327680 fl
  unsigned short* ke   = (unsigned short*)(ws + 4719232);  // 327680 fl
  unsigned short* qbf  = (unsigned short*)(ws + 5046912);  // 524288 fl
  unsigned short* kbf  = (unsigned short*)(ws + 5571200);  // 524288 fl
  unsigned short* vtb  = (unsigned short*)(ws + 6095488);  // 393216 fl
  unsigned short* wbf  = (unsigned short*)(ws + 6488704);  // 512000 fl
  unsigned short* th   = (unsigned short*)(ws + 7000704);  // 8388608 fl ([B,H,N,M] bf16)
  float* out = (float*)d_out;
  unsigned short* qk_wb   = wbf;
  unsigned short* qkv_wb  = wbf + 204800;
  unsigned short* proj_wb = wbf + 819200;

  hipLaunchKernelGGL(k_trans, dim3(32, 10, 2), dim3(256), 0, stream, x, node, nodebf);
  hipLaunchKernelGGL(k_svec, dim3(2), dim3(320), 0, stream, da, fcp_w, fcp_b, svec);
  hipLaunchKernelGGL(k_wcvt, dim3(512), dim3(256), 0, stream,
                     qk_w, 204800, qkv_w, 614400, proj_w, 204800, wbf,
                     (uint4*)qbf, 262144);
  hipLaunchKernelGGL(k_mgemm, dim3(32, 10), dim3(256), 0, stream,
                     nodebf, qk_wb, (const float*)nullptr, qe, ke, (void*)nullptr, 1);
  hipLaunchKernelGGL(k_edge3, dim3(64, 2), dim3(512), 0, stream, qe, ke, edge);
  for (int l = 0; l < 2; ++l) {
    hipLaunchKernelGGL(k_ln, dim3(512), dim3(256), 0, stream, node, edge, svec,
                       ln1_g + l * 320, ln1_b + l * 320, gln_g + l * 320, gln_b + l * 320, ybf);
    hipLaunchKernelGGL(k_mgemm, dim3(32, 15), dim3(256), 0, stream,
                       ybf, qkv_wb + (size_t)l * 307200, qkv_b + l * 960, qbf, kbf, vtb, 2);
    hipLaunchKernelGGL(k_score3, dim3(64, 8, 2), dim3(256), 0, stream,
                       qbf, kbf, vtb, edge, th, attb,
                       exp_w + l * 8, exp_b + l * 8, red_w + l * 8);
    hipLaunchKernelGGL(k_wsum, dim3(512), dim3(256), 0, stream,
                       th, edge, attb, attbf, red_b + l);
    if (l == 0)
      hipLaunchKernelGGL(k_mgemm, dim3(32, 5), dim3(256), 0, stream,
                         attbf, proj_wb, proj_b, node, (void*)nullptr, (void*)nullptr, 0);
    else
      hipLaunchKernelGGL(k_mgemm, dim3(32, 5), dim3(256), 0, stream,
                         attbf, proj_wb + 102400, proj_b + 320, out,
                         (void*)nullptr, (void*)nullptr, 3);
  }
}